// Round 4
// baseline (1146.236 us; speedup 1.0000x reference)
//
#include <hip/hip_runtime.h>
#include <hip/hip_bf16.h>

#define NEG_SLOPE 0.2f

// ---------------------------------------------------------------------------
// GEMM v3: streaming, no LDS, no barriers.
// grid = (ceil(n/64), 4 heads), block = 256 (4 waves).
// wave w handles 64 rows (lane = row) x 16 cols [w*16..w*16+15] of head h.
// X rows read per-lane (L1-sequential, shared across block's waves);
// W read at wave-uniform addresses (single-line L1 broadcast).
// Fused attention projections via atomicAdd into zeroed as_/at_.
// ---------------------------------------------------------------------------
__global__ __launch_bounds__(256) void gemm_fused_k(
    const float* __restrict__ X,      // [n,256]
    const float* __restrict__ W,      // [4,256,64]
    const float* __restrict__ a_src,  // [4,64]
    const float* __restrict__ a_trg,  // [4,64]
    float* __restrict__ HP,           // [n,256]  col = h*64+f
    float* __restrict__ as_,          // [n,4] (zeroed)
    float* __restrict__ at_,          // [n,4] (zeroed)
    int n)
{
    const int t = threadIdx.x;
    const int w = t >> 6;             // wave 0..3 -> col chunk
    const int l = t & 63;             // lane = row within tile
    const int h = blockIdx.y;
    const int row_u = blockIdx.x * 64 + l;
    const bool valid = row_u < n;
    const int row = valid ? row_u : (n - 1);
    const int f0 = w * 16;

    const float* xrow = X + (size_t)row * 256;
    const float* bcol = W + (size_t)h * 16384 + f0;   // +k*64 walks k

    float acc[16];
    #pragma unroll
    for (int j = 0; j < 16; ++j) acc[j] = 0.f;

    #pragma unroll 2
    for (int k = 0; k < 256; k += 4) {
        float xv[4];
        *(float4*)xv = *(const float4*)(xrow + k);
        #pragma unroll
        for (int kk = 0; kk < 4; ++kk) {
            const float* br = bcol + (size_t)(k + kk) * 64;
            float bv[16];
            *(float4*)&bv[0]  = *(const float4*)(br + 0);
            *(float4*)&bv[4]  = *(const float4*)(br + 4);
            *(float4*)&bv[8]  = *(const float4*)(br + 8);
            *(float4*)&bv[12] = *(const float4*)(br + 12);
            const float xs = xv[kk];
            #pragma unroll
            for (int j = 0; j < 16; ++j) acc[j] += xs * bv[j];
        }
    }

    if (valid) {
        float* hrow = HP + (size_t)row * 256 + h * 64 + f0;
        *(float4*)(hrow + 0)  = *(float4*)&acc[0];
        *(float4*)(hrow + 4)  = *(float4*)&acc[4];
        *(float4*)(hrow + 8)  = *(float4*)&acc[8];
        *(float4*)(hrow + 12) = *(float4*)&acc[12];

        const float* pa = a_src + h * 64 + f0;
        const float* pb = a_trg + h * 64 + f0;
        float ps = 0.f, pt_ = 0.f;
        #pragma unroll
        for (int j = 0; j < 16; ++j) {
            ps  += acc[j] * pa[j];
            pt_ += acc[j] * pb[j];
        }
        atomicAdd(&as_[row * 4 + h], ps);
        atomicAdd(&at_[row * 4 + h], pt_);
    }
}

// ---------------------------------------------------------------------------
// CSR build: histogram -> scan -> scatter src values sorted by trg
// ---------------------------------------------------------------------------
__global__ void hist_k(const int* __restrict__ trg, int* __restrict__ counts,
                       int* __restrict__ ranks, int E)
{
    int e = blockIdx.x * blockDim.x + threadIdx.x;
    if (e < E) ranks[e] = atomicAdd(&counts[trg[e]], 1);
}

__global__ __launch_bounds__(1024) void scan_k(const int* __restrict__ counts,
                                               int* __restrict__ starts, int n)
{
    const int T = 1024;
    int t = threadIdx.x;
    int chunk = (n + T - 1) / T;
    int beg = t * chunk;
    int end = min(beg + chunk, n);
    int sum = 0;
    for (int i = beg; i < end; ++i) sum += counts[i];
    __shared__ int lds[T];
    lds[t] = sum;
    __syncthreads();
    for (int off = 1; off < T; off <<= 1) {
        int v = (t >= off) ? lds[t - off] : 0;
        __syncthreads();
        lds[t] += v;
        __syncthreads();
    }
    int run = lds[t] - sum;
    for (int i = beg; i < end; ++i) { starts[i] = run; run += counts[i]; }
    if (t == T - 1) starts[n] = lds[T - 1];
}

__global__ void scatter_k(const int* __restrict__ src, const int* __restrict__ trg,
                          const int* __restrict__ starts, const int* __restrict__ ranks,
                          int* __restrict__ srcs, int E)
{
    int e = blockIdx.x * blockDim.x + threadIdx.x;
    if (e < E) srcs[starts[trg[e]] + ranks[e]] = src[e];
}

// ---------------------------------------------------------------------------
// Aggregation, one WAVE per node, 2-edge unroll w/ dual accumulators.
// lane l: cols 4l..4l+3 of hp row (head h = l>>4).
// out = (sum_e p_e * hp[src_e]) / (sum_e p_e + 1e-16)
// LAYER 0: elu -> buf[n][256].  LAYER 1: head-mean -> out[n][64].
// ---------------------------------------------------------------------------
template<int LAYER>
__global__ __launch_bounds__(256) void aggregate_k(
    const float* __restrict__ HP, const float* __restrict__ as_,
    const float* __restrict__ at_, const int* __restrict__ starts,
    const int* __restrict__ srcs, float* __restrict__ out, int n)
{
    const int w = threadIdx.x >> 6;
    const int l = threadIdx.x & 63;
    const int v = blockIdx.x * 4 + w;
    if (v >= n) return;
    const int h = l >> 4;
    const int s0 = starts[v];
    const int s1 = starts[v + 1];
    const float atv = at_[v * 4 + h];

    float4 ac0 = make_float4(0.f, 0.f, 0.f, 0.f);
    float4 ac1 = make_float4(0.f, 0.f, 0.f, 0.f);
    float den0 = 0.f, den1 = 0.f;

    for (int base = s0; base < s1; base += 64) {
        int m = min(64, s1 - base);
        int s_l = (base + l < s1) ? srcs[base + l] : 0;
        int i = 0;
        for (; i + 1 < m; i += 2) {
            int sa = __shfl(s_l, i, 64);
            int sb = __shfl(s_l, i + 1, 64);
            float ea = as_[sa * 4 + h] + atv;
            float eb = as_[sb * 4 + h] + atv;
            float4 ha = *(const float4*)(HP + (size_t)sa * 256 + l * 4);
            float4 hb = *(const float4*)(HP + (size_t)sb * 256 + l * 4);
            ea = (ea > 0.f) ? ea : NEG_SLOPE * ea;
            eb = (eb > 0.f) ? eb : NEG_SLOPE * eb;
            float pA = expf(ea), pB = expf(eb);
            den0 += pA; den1 += pB;
            ac0.x += pA * ha.x; ac0.y += pA * ha.y;
            ac0.z += pA * ha.z; ac0.w += pA * ha.w;
            ac1.x += pB * hb.x; ac1.y += pB * hb.y;
            ac1.z += pB * hb.z; ac1.w += pB * hb.w;
        }
        if (i < m) {
            int sa = __shfl(s_l, i, 64);
            float ea = as_[sa * 4 + h] + atv;
            float4 ha = *(const float4*)(HP + (size_t)sa * 256 + l * 4);
            ea = (ea > 0.f) ? ea : NEG_SLOPE * ea;
            float pA = expf(ea);
            den0 += pA;
            ac0.x += pA * ha.x; ac0.y += pA * ha.y;
            ac0.z += pA * ha.z; ac0.w += pA * ha.w;
        }
    }

    float4 acc = make_float4(ac0.x + ac1.x, ac0.y + ac1.y,
                             ac0.z + ac1.z, ac0.w + ac1.w);
    float r = 1.f / (den0 + den1 + 1e-16f);
    acc.x *= r; acc.y *= r; acc.z *= r; acc.w *= r;

    if (LAYER == 0) {
        acc.x = (acc.x > 0.f) ? acc.x : expm1f(acc.x);
        acc.y = (acc.y > 0.f) ? acc.y : expm1f(acc.y);
        acc.z = (acc.z > 0.f) ? acc.z : expm1f(acc.z);
        acc.w = (acc.w > 0.f) ? acc.w : expm1f(acc.w);
        *(float4*)(out + (size_t)v * 256 + l * 4) = acc;
    } else {
        acc.x += __shfl_xor(acc.x, 16, 64); acc.y += __shfl_xor(acc.y, 16, 64);
        acc.z += __shfl_xor(acc.z, 16, 64); acc.w += __shfl_xor(acc.w, 16, 64);
        acc.x += __shfl_xor(acc.x, 32, 64); acc.y += __shfl_xor(acc.y, 32, 64);
        acc.z += __shfl_xor(acc.z, 32, 64); acc.w += __shfl_xor(acc.w, 32, 64);
        if (l < 16) {
            acc.x *= 0.25f; acc.y *= 0.25f; acc.z *= 0.25f; acc.w *= 0.25f;
            *(float4*)(out + (size_t)v * 64 + l * 4) = acc;
        }
    }
}

// ---------------------------------------------------------------------------
// final: logits = [out_u | out_t] @ fc_w + fc_b ; log_softmax over 16
// ---------------------------------------------------------------------------
__global__ __launch_bounds__(256) void final_k(
    const float* __restrict__ out_u, const float* __restrict__ out_t,
    const float* __restrict__ fcw, const float* __restrict__ fcb,
    float* __restrict__ out, int nret)
{
    int gid = blockIdx.x * blockDim.x + threadIdx.x;
    int nn = gid >> 4;
    int j  = gid & 15;
    if (nn >= nret) return;
    const float* ru = out_u + (size_t)nn * 64;
    const float* rt = out_t + (size_t)nn * 64;
    float acc = fcb[j];
    #pragma unroll 8
    for (int k = 0; k < 64; ++k) acc += ru[k] * fcw[k * 16 + j];
    #pragma unroll 8
    for (int k = 0; k < 64; ++k) acc += rt[k] * fcw[(64 + k) * 16 + j];

    float m = acc;
    for (int off = 8; off; off >>= 1) m = fmaxf(m, __shfl_xor(m, off, 16));
    float ex = expf(acc - m);
    float s = ex;
    for (int off = 8; off; off >>= 1) s += __shfl_xor(s, off, 16);
    out[(size_t)nn * 16 + j] = acc - m - logf(s);
}

// ---------------------------------------------------------------------------
extern "C" void kernel_launch(void* const* d_in, const int* in_sizes, int n_in,
                              void* d_out, int out_size, void* d_ws, size_t ws_size,
                              hipStream_t stream)
{
    const int N = in_sizes[0] / 256;     // 20000
    const int E = in_sizes[2];           // 320000
    const int NRET = out_size / 16;      // 20000

    const float* emb[2]  = { (const float*)d_in[0], (const float*)d_in[1] };
    const int*   srcI[2] = { (const int*)d_in[2], (const int*)d_in[4] };
    const int*   trgI[2] = { (const int*)d_in[3], (const int*)d_in[5] };
    const float* fcw = (const float*)d_in[18];
    const float* fcb = (const float*)d_in[19];

    // workspace layout
    float* hp    = (float*)d_ws;                      // N*256
    float* buf   = hp + (size_t)N * 256;              // N*256
    float* as_   = buf + (size_t)N * 256;             // N*4
    float* at_   = as_ + (size_t)N * 4;               // N*4  (adjacent: one memset)
    float* out_s[2];
    out_s[0] = at_ + (size_t)N * 4;                   // N*64
    out_s[1] = out_s[0] + (size_t)N * 64;             // N*64
    int* starts  = (int*)(out_s[1] + (size_t)N * 64); // N+1
    int* counts  = starts + (N + 1);                  // N
    int* ranks   = counts + N;                        // E
    int* srcs    = ranks + E;                         // E

    const int EB = (E + 255) / 256;
    const dim3 gemm_grid((N + 63) / 64, 4);
    const int agg_grid = (N + 3) / 4;

    for (int side = 0; side < 2; ++side) {
        // CSR build (shared by both layers of this side)
        hipMemsetAsync(counts, 0, (size_t)N * sizeof(int), stream);
        hist_k<<<EB, 256, 0, stream>>>(trgI[side], counts, ranks, E);
        scan_k<<<1, 1024, 0, stream>>>(counts, starts, N);
        scatter_k<<<EB, 256, 0, stream>>>(srcI[side], trgI[side], starts, ranks, srcs, E);

        for (int layer = 0; layer < 2; ++layer) {
            const float* wl  = (const float*)d_in[6 + side * 6 + layer * 3 + 0];
            const float* asl = (const float*)d_in[6 + side * 6 + layer * 3 + 1];
            const float* atl = (const float*)d_in[6 + side * 6 + layer * 3 + 2];
            const float* x   = (layer == 0) ? emb[side] : buf;

            hipMemsetAsync(as_, 0, (size_t)N * 8 * sizeof(float), stream);
            gemm_fused_k<<<gemm_grid, 256, 0, stream>>>(x, wl, asl, atl,
                                                        hp, as_, at_, N);
            if (layer == 0)
                aggregate_k<0><<<agg_grid, 256, 0, stream>>>(hp, as_, at_, starts,
                                                             srcs, buf, N);
            else
                aggregate_k<1><<<agg_grid, 256, 0, stream>>>(hp, as_, at_, starts,
                                                             srcs, out_s[side], N);
        }
    }

    final_k<<<(NRET * 16 + 255) / 256, 256, 0, stream>>>(out_s[0], out_s[1], fcw, fcb,
                                                         (float*)d_out, NRET);
}

// Round 5
// 541.088 us; speedup vs baseline: 2.1184x; 2.1184x over previous
//
#include <hip/hip_runtime.h>
#include <hip/hip_bf16.h>

#define NEG_SLOPE 0.2f

typedef unsigned short u16;
typedef u16 u16x8 __attribute__((ext_vector_type(8)));
typedef u16 u16x4 __attribute__((ext_vector_type(4)));
typedef short s16x8 __attribute__((ext_vector_type(8)));
typedef float f32x4 __attribute__((ext_vector_type(4)));

__device__ __forceinline__ u16 f2bf(float x) {
    unsigned u = __float_as_uint(x);
    return (u16)((u + 0x7fffu + ((u >> 16) & 1u)) >> 16);
}
__device__ __forceinline__ float bf2f(u16 h) {
    return __uint_as_float(((unsigned)h) << 16);
}

// ---------------------------------------------------------------------------
// split fp32 -> bf16 hi + bf16 lo(residual). 4 floats/thread.
// ---------------------------------------------------------------------------
__global__ __launch_bounds__(256) void splitx_k(const float* __restrict__ X,
                                                u16* __restrict__ Xh,
                                                u16* __restrict__ Xl, int total4)
{
    int i = blockIdx.x * 256 + threadIdx.x;
    if (i >= total4) return;
    float4 v = *(const float4*)(X + (size_t)i * 4);
    float f[4] = { v.x, v.y, v.z, v.w };
    u16x4 hi, lo;
    #pragma unroll
    for (int j = 0; j < 4; ++j) {
        u16 h = f2bf(f[j]);
        hi[j] = h;
        lo[j] = f2bf(f[j] - bf2f(h));
    }
    *(u16x4*)(Xh + (size_t)i * 4) = hi;
    *(u16x4*)(Xl + (size_t)i * 4) = lo;
}

// ---------------------------------------------------------------------------
// W [4][256][64] (h,k,f) -> Wct [256 cols][256 k] bf16 hi/lo, col = h*64+f
// ---------------------------------------------------------------------------
__global__ __launch_bounds__(256) void wsplit_k(const float* __restrict__ W,
                                                u16* __restrict__ Wht,
                                                u16* __restrict__ Wlt)
{
    int tid = blockIdx.x * 256 + threadIdx.x;   // 0..65535
    int f = tid & 63, k = (tid >> 6) & 255, h = tid >> 14;
    float x = W[tid];
    u16 hi = f2bf(x);
    u16 lo = f2bf(x - bf2f(hi));
    int o = (h * 64 + f) * 256 + k;
    Wht[o] = hi; Wlt[o] = lo;
}

// ---------------------------------------------------------------------------
// MFMA GEMM (bf16x3 split): HP[n][256] = X @ Wc, block tile 64 rows x 64 cols
// (one head), 4 waves as 2x2 of 32x32 wave tiles, K-step 32.
// LDS row stride 40 u16 (80B): frag reads provably conflict-free.
// Frag layout (m89/m92): A lane: row=l&15, k=(l>>4)*8+j ; B: col=l&15, same k.
// C/D: col=lane&15, row=(lane>>4)*4+reg.
// ---------------------------------------------------------------------------
__global__ __launch_bounds__(256) void gemm_mfma_k(
    const u16* __restrict__ Xh, const u16* __restrict__ Xl,
    const u16* __restrict__ Wht, const u16* __restrict__ Wlt,
    float* __restrict__ HP, int n)
{
    const int row0 = blockIdx.x * 64;
    const int h    = blockIdx.y;
    const int t = threadIdx.x;
    const int l = t & 63;
    const int wc = (t >> 6) & 1;      // col half of wave
    const int wr = (t >> 7) & 1;      // row half of wave

    __shared__ u16 Ah[64 * 40], Al[64 * 40], Bh[64 * 40], Bl[64 * 40];

    // staging: thread t -> row/col sr = t>>2, 16B chunk sp = t&3
    const int sr = t >> 2, sp = t & 3;
    const int arow = (row0 + sr < n) ? (row0 + sr) : (n - 1);
    const u16* gAh = Xh + (size_t)arow * 256 + sp * 8;
    const u16* gAl = Xl + (size_t)arow * 256 + sp * 8;
    const u16* gBh = Wht + (size_t)(h * 64 + sr) * 256 + sp * 8;
    const u16* gBl = Wlt + (size_t)(h * 64 + sr) * 256 + sp * 8;
    const int ldst = sr * 40 + sp * 8;

    const int ra0 = (wr * 32 + (l & 15)) * 40 + (l >> 4) * 8;
    const int ca0 = (wc * 32 + (l & 15)) * 40 + (l >> 4) * 8;

    f32x4 acc00 = {0.f, 0.f, 0.f, 0.f}, acc01 = acc00, acc10 = acc00, acc11 = acc00;

    for (int k0 = 0; k0 < 256; k0 += 32) {
        __syncthreads();
        *(u16x8*)&Ah[ldst] = *(const u16x8*)(gAh + k0);
        *(u16x8*)&Al[ldst] = *(const u16x8*)(gAl + k0);
        *(u16x8*)&Bh[ldst] = *(const u16x8*)(gBh + k0);
        *(u16x8*)&Bl[ldst] = *(const u16x8*)(gBl + k0);
        __syncthreads();

        s16x8 a0h = *(const s16x8*)&Ah[ra0];
        s16x8 a1h = *(const s16x8*)&Ah[ra0 + 640];
        s16x8 a0l = *(const s16x8*)&Al[ra0];
        s16x8 a1l = *(const s16x8*)&Al[ra0 + 640];
        s16x8 b0h = *(const s16x8*)&Bh[ca0];
        s16x8 b1h = *(const s16x8*)&Bh[ca0 + 640];
        s16x8 b0l = *(const s16x8*)&Bl[ca0];
        s16x8 b1l = *(const s16x8*)&Bl[ca0 + 640];

        // hi*hi
        acc00 = __builtin_amdgcn_mfma_f32_16x16x32_bf16(a0h, b0h, acc00, 0, 0, 0);
        acc01 = __builtin_amdgcn_mfma_f32_16x16x32_bf16(a0h, b1h, acc01, 0, 0, 0);
        acc10 = __builtin_amdgcn_mfma_f32_16x16x32_bf16(a1h, b0h, acc10, 0, 0, 0);
        acc11 = __builtin_amdgcn_mfma_f32_16x16x32_bf16(a1h, b1h, acc11, 0, 0, 0);
        // hi*lo
        acc00 = __builtin_amdgcn_mfma_f32_16x16x32_bf16(a0h, b0l, acc00, 0, 0, 0);
        acc01 = __builtin_amdgcn_mfma_f32_16x16x32_bf16(a0h, b1l, acc01, 0, 0, 0);
        acc10 = __builtin_amdgcn_mfma_f32_16x16x32_bf16(a1h, b0l, acc10, 0, 0, 0);
        acc11 = __builtin_amdgcn_mfma_f32_16x16x32_bf16(a1h, b1l, acc11, 0, 0, 0);
        // lo*hi
        acc00 = __builtin_amdgcn_mfma_f32_16x16x32_bf16(a0l, b0h, acc00, 0, 0, 0);
        acc01 = __builtin_amdgcn_mfma_f32_16x16x32_bf16(a0l, b1h, acc01, 0, 0, 0);
        acc10 = __builtin_amdgcn_mfma_f32_16x16x32_bf16(a1l, b0h, acc10, 0, 0, 0);
        acc11 = __builtin_amdgcn_mfma_f32_16x16x32_bf16(a1l, b1h, acc11, 0, 0, 0);
    }

    // epilogue: C/D mapping col=l&15, row=(l>>4)*4+r
    const int cb = h * 64 + wc * 32 + (l & 15);
    const int rb = row0 + wr * 32 + (l >> 4) * 4;
    #pragma unroll
    for (int r = 0; r < 4; ++r) {
        int g0 = rb + r;
        if (g0 < n) {
            HP[(size_t)g0 * 256 + cb]      = acc00[r];
            HP[(size_t)g0 * 256 + cb + 16] = acc01[r];
        }
        int g1 = rb + 16 + r;
        if (g1 < n) {
            HP[(size_t)g1 * 256 + cb]      = acc10[r];
            HP[(size_t)g1 * 256 + cb + 16] = acc11[r];
        }
    }
}

// ---------------------------------------------------------------------------
// attention projections: 16 lanes per (node,head); shuffle reduce width 16.
// ---------------------------------------------------------------------------
__global__ __launch_bounds__(256) void attn_proj_k(
    const float* __restrict__ HP, const float* __restrict__ a_src,
    const float* __restrict__ a_trg,
    float* __restrict__ as_, float* __restrict__ at_, int n)
{
    int tid = blockIdx.x * 256 + threadIdx.x;
    int nn = tid >> 4, q = tid & 15;
    if (nn >= n) return;
    int h = blockIdx.y;
    float4 v = *(const float4*)(HP + (size_t)nn * 256 + h * 64 + q * 4);
    float4 pa = *(const float4*)(a_src + h * 64 + q * 4);
    float4 pb = *(const float4*)(a_trg + h * 64 + q * 4);
    float s = v.x * pa.x + v.y * pa.y + v.z * pa.z + v.w * pa.w;
    float u = v.x * pb.x + v.y * pb.y + v.z * pb.z + v.w * pb.w;
    for (int off = 8; off; off >>= 1) {
        s += __shfl_xor(s, off, 16);
        u += __shfl_xor(u, off, 16);
    }
    if (q == 0) { as_[nn * 4 + h] = s; at_[nn * 4 + h] = u; }
}

// ---------------------------------------------------------------------------
// CSR build: histogram -> scan -> scatter src values sorted by trg
// ---------------------------------------------------------------------------
__global__ void hist_k(const int* __restrict__ trg, int* __restrict__ counts,
                       int* __restrict__ ranks, int E)
{
    int e = blockIdx.x * blockDim.x + threadIdx.x;
    if (e < E) ranks[e] = atomicAdd(&counts[trg[e]], 1);
}

__global__ __launch_bounds__(1024) void scan_k(const int* __restrict__ counts,
                                               int* __restrict__ starts, int n)
{
    const int T = 1024;
    int t = threadIdx.x;
    int chunk = (n + T - 1) / T;
    int beg = t * chunk;
    int end = min(beg + chunk, n);
    int sum = 0;
    for (int i = beg; i < end; ++i) sum += counts[i];
    __shared__ int lds[T];
    lds[t] = sum;
    __syncthreads();
    for (int off = 1; off < T; off <<= 1) {
        int v = (t >= off) ? lds[t - off] : 0;
        __syncthreads();
        lds[t] += v;
        __syncthreads();
    }
    int run = lds[t] - sum;
    for (int i = beg; i < end; ++i) { starts[i] = run; run += counts[i]; }
    if (t == T - 1) starts[n] = lds[T - 1];
}

__global__ void scatter_k(const int* __restrict__ src, const int* __restrict__ trg,
                          const int* __restrict__ starts, const int* __restrict__ ranks,
                          int* __restrict__ srcs, int E)
{
    int e = blockIdx.x * blockDim.x + threadIdx.x;
    if (e < E) srcs[starts[trg[e]] + ranks[e]] = src[e];
}

// ---------------------------------------------------------------------------
// Aggregation, one WAVE per node, 2-edge unroll w/ dual accumulators.
// ---------------------------------------------------------------------------
template<int LAYER>
__global__ __launch_bounds__(256) void aggregate_k(
    const float* __restrict__ HP, const float* __restrict__ as_,
    const float* __restrict__ at_, const int* __restrict__ starts,
    const int* __restrict__ srcs, float* __restrict__ out, int n)
{
    const int w = threadIdx.x >> 6;
    const int l = threadIdx.x & 63;
    const int v = blockIdx.x * 4 + w;
    if (v >= n) return;
    const int h = l >> 4;
    const int s0 = starts[v];
    const int s1 = starts[v + 1];
    const float atv = at_[v * 4 + h];

    float4 ac0 = make_float4(0.f, 0.f, 0.f, 0.f);
    float4 ac1 = make_float4(0.f, 0.f, 0.f, 0.f);
    float den0 = 0.f, den1 = 0.f;

    for (int base = s0; base < s1; base += 64) {
        int m = min(64, s1 - base);
        int s_l = (base + l < s1) ? srcs[base + l] : 0;
        int i = 0;
        for (; i + 1 < m; i += 2) {
            int sa = __shfl(s_l, i, 64);
            int sb = __shfl(s_l, i + 1, 64);
            float ea = as_[sa * 4 + h] + atv;
            float eb = as_[sb * 4 + h] + atv;
            float4 ha = *(const float4*)(HP + (size_t)sa * 256 + l * 4);
            float4 hb = *(const float4*)(HP + (size_t)sb * 256 + l * 4);
            ea = (ea > 0.f) ? ea : NEG_SLOPE * ea;
            eb = (eb > 0.f) ? eb : NEG_SLOPE * eb;
            float pA = expf(ea), pB = expf(eb);
            den0 += pA; den1 += pB;
            ac0.x += pA * ha.x; ac0.y += pA * ha.y;
            ac0.z += pA * ha.z; ac0.w += pA * ha.w;
            ac1.x += pB * hb.x; ac1.y += pB * hb.y;
            ac1.z += pB * hb.z; ac1.w += pB * hb.w;
        }
        if (i < m) {
            int sa = __shfl(s_l, i, 64);
            float ea = as_[sa * 4 + h] + atv;
            float4 ha = *(const float4*)(HP + (size_t)sa * 256 + l * 4);
            ea = (ea > 0.f) ? ea : NEG_SLOPE * ea;
            float pA = expf(ea);
            den0 += pA;
            ac0.x += pA * ha.x; ac0.y += pA * ha.y;
            ac0.z += pA * ha.z; ac0.w += pA * ha.w;
        }
    }

    float4 acc = make_float4(ac0.x + ac1.x, ac0.y + ac1.y,
                             ac0.z + ac1.z, ac0.w + ac1.w);
    float r = 1.f / (den0 + den1 + 1e-16f);
    acc.x *= r; acc.y *= r; acc.z *= r; acc.w *= r;

    if (LAYER == 0) {
        acc.x = (acc.x > 0.f) ? acc.x : expm1f(acc.x);
        acc.y = (acc.y > 0.f) ? acc.y : expm1f(acc.y);
        acc.z = (acc.z > 0.f) ? acc.z : expm1f(acc.z);
        acc.w = (acc.w > 0.f) ? acc.w : expm1f(acc.w);
        *(float4*)(out + (size_t)v * 256 + l * 4) = acc;
    } else {
        acc.x += __shfl_xor(acc.x, 16, 64); acc.y += __shfl_xor(acc.y, 16, 64);
        acc.z += __shfl_xor(acc.z, 16, 64); acc.w += __shfl_xor(acc.w, 16, 64);
        acc.x += __shfl_xor(acc.x, 32, 64); acc.y += __shfl_xor(acc.y, 32, 64);
        acc.z += __shfl_xor(acc.z, 32, 64); acc.w += __shfl_xor(acc.w, 32, 64);
        if (l < 16) {
            acc.x *= 0.25f; acc.y *= 0.25f; acc.z *= 0.25f; acc.w *= 0.25f;
            *(float4*)(out + (size_t)v * 64 + l * 4) = acc;
        }
    }
}

// ---------------------------------------------------------------------------
// final: logits = [out_u | out_t] @ fc_w + fc_b ; log_softmax over 16
// ---------------------------------------------------------------------------
__global__ __launch_bounds__(256) void final_k(
    const float* __restrict__ out_u, const float* __restrict__ out_t,
    const float* __restrict__ fcw, const float* __restrict__ fcb,
    float* __restrict__ out, int nret)
{
    int gid = blockIdx.x * blockDim.x + threadIdx.x;
    int nn = gid >> 4;
    int j  = gid & 15;
    if (nn >= nret) return;
    const float* ru = out_u + (size_t)nn * 64;
    const float* rt = out_t + (size_t)nn * 64;
    float acc = fcb[j];
    #pragma unroll 8
    for (int k = 0; k < 64; ++k) acc += ru[k] * fcw[k * 16 + j];
    #pragma unroll 8
    for (int k = 0; k < 64; ++k) acc += rt[k] * fcw[(64 + k) * 16 + j];

    float m = acc;
    for (int off = 8; off; off >>= 1) m = fmaxf(m, __shfl_xor(m, off, 16));
    float ex = expf(acc - m);
    float s = ex;
    for (int off = 8; off; off >>= 1) s += __shfl_xor(s, off, 16);
    out[(size_t)nn * 16 + j] = acc - m - logf(s);
}

// ---------------------------------------------------------------------------
extern "C" void kernel_launch(void* const* d_in, const int* in_sizes, int n_in,
                              void* d_out, int out_size, void* d_ws, size_t ws_size,
                              hipStream_t stream)
{
    const int N = in_sizes[0] / 256;     // 20000
    const int E = in_sizes[2];           // 320000
    const int NRET = out_size / 16;      // 20000

    const float* emb[2]  = { (const float*)d_in[0], (const float*)d_in[1] };
    const int*   srcI[2] = { (const int*)d_in[2], (const int*)d_in[4] };
    const int*   trgI[2] = { (const int*)d_in[3], (const int*)d_in[5] };
    const float* fcw = (const float*)d_in[18];
    const float* fcb = (const float*)d_in[19];

    // workspace layout (16B-aligned regions)
    float* hp    = (float*)d_ws;                      // N*256
    float* buf   = hp + (size_t)N * 256;              // N*256
    float* as_   = buf + (size_t)N * 256;             // N*4
    float* at_   = as_ + (size_t)N * 4;               // N*4
    float* out_s[2];
    out_s[0] = at_ + (size_t)N * 4;                   // N*64
    out_s[1] = out_s[0] + (size_t)N * 64;             // N*64
    u16* xh  = (u16*)(out_s[1] + (size_t)N * 64);     // N*256 u16
    u16* xl  = xh + (size_t)N * 256;                  // N*256 u16
    u16* wht = xl + (size_t)N * 256;                  // 65536 u16
    u16* wlt = wht + 65536;                           // 65536 u16
    int* starts = (int*)(wlt + 65536);                // N+1
    int* counts = starts + (N + 1);                   // N
    int* ranks  = counts + N;                         // E
    int* srcs   = ranks + E;                          // E

    const int EB = (E + 255) / 256;
    const dim3 gemm_grid((N + 63) / 64, 4);
    const dim3 proj_grid((N * 16 + 255) / 256, 4);
    const int split_blocks = (N * 256 / 4 + 255) / 256;
    const int agg_grid = (N + 3) / 4;

    for (int side = 0; side < 2; ++side) {
        // CSR build (shared by both layers of this side)
        hipMemsetAsync(counts, 0, (size_t)N * sizeof(int), stream);
        hist_k<<<EB, 256, 0, stream>>>(trgI[side], counts, ranks, E);
        scan_k<<<1, 1024, 0, stream>>>(counts, starts, N);
        scatter_k<<<EB, 256, 0, stream>>>(srcI[side], trgI[side], starts, ranks, srcs, E);

        for (int layer = 0; layer < 2; ++layer) {
            const float* wl  = (const float*)d_in[6 + side * 6 + layer * 3 + 0];
            const float* asl = (const float*)d_in[6 + side * 6 + layer * 3 + 1];
            const float* atl = (const float*)d_in[6 + side * 6 + layer * 3 + 2];
            const float* x   = (layer == 0) ? emb[side] : buf;

            wsplit_k<<<256, 256, 0, stream>>>(wl, wht, wlt);
            splitx_k<<<split_blocks, 256, 0, stream>>>(x, xh, xl, N * 64);
            gemm_mfma_k<<<gemm_grid, 256, 0, stream>>>(xh, xl, wht, wlt, hp, N);
            attn_proj_k<<<proj_grid, 256, 0, stream>>>(hp, asl, atl, as_, at_, N);
            if (layer == 0)
                aggregate_k<0><<<agg_grid, 256, 0, stream>>>(hp, as_, at_, starts,
                                                             srcs, buf, N);
            else
                aggregate_k<1><<<agg_grid, 256, 0, stream>>>(hp, as_, at_, starts,
                                                             srcs, out_s[side], N);
        }
    }

    final_k<<<(NRET * 16 + 255) / 256, 256, 0, stream>>>(out_s[0], out_s[1], fcw, fcb,
                                                         (float*)d_out, NRET);
}

// Round 7
// 453.100 us; speedup vs baseline: 2.5298x; 1.1942x over previous
//
#include <hip/hip_runtime.h>
#include <hip/hip_bf16.h>

#define NEG_SLOPE 0.2f

typedef unsigned short u16;
typedef u16 u16x8 __attribute__((ext_vector_type(8)));
typedef u16 u16x4 __attribute__((ext_vector_type(4)));
typedef short s16x8 __attribute__((ext_vector_type(8)));
typedef float f32x4 __attribute__((ext_vector_type(4)));

__device__ __forceinline__ u16 f2bf(float x) {
    unsigned u = __float_as_uint(x);
    return (u16)((u + 0x7fffu + ((u >> 16) & 1u)) >> 16);
}
__device__ __forceinline__ float bf2f(u16 h) {
    return __uint_as_float(((unsigned)h) << 16);
}

// ---------------------------------------------------------------------------
// split fp32 -> bf16 hi + bf16 lo(residual). 4 floats/thread.
// ---------------------------------------------------------------------------
__global__ __launch_bounds__(256) void splitx_k(const float* __restrict__ X,
                                                u16* __restrict__ Xh,
                                                u16* __restrict__ Xl, int total4)
{
    int i = blockIdx.x * 256 + threadIdx.x;
    if (i >= total4) return;
    float4 v = *(const float4*)(X + (size_t)i * 4);
    float f[4] = { v.x, v.y, v.z, v.w };
    u16x4 hi, lo;
    #pragma unroll
    for (int j = 0; j < 4; ++j) {
        u16 h = f2bf(f[j]);
        hi[j] = h;
        lo[j] = f2bf(f[j] - bf2f(h));
    }
    *(u16x4*)(Xh + (size_t)i * 4) = hi;
    *(u16x4*)(Xl + (size_t)i * 4) = lo;
}

// ---------------------------------------------------------------------------
// all 4 weight tensors at once: W[h][k][f] -> Wct[which][col=h*64+f][k] hi/lo
// ---------------------------------------------------------------------------
__global__ __launch_bounds__(256) void wsplit4_k(
    const float* __restrict__ w0, const float* __restrict__ w1,
    const float* __restrict__ w2, const float* __restrict__ w3,
    u16* __restrict__ Wht, u16* __restrict__ Wlt)
{
    int tid = blockIdx.x * 256 + threadIdx.x;     // 0..262143
    int which = tid >> 16;
    int idx = tid & 65535;
    const float* W = (which == 0) ? w0 : (which == 1) ? w1 : (which == 2) ? w2 : w3;
    int f = idx & 63, k = (idx >> 6) & 255, h = idx >> 14;
    float x = W[idx];
    u16 hi = f2bf(x);
    u16 lo = f2bf(x - bf2f(hi));
    int o = (which << 16) + (h * 64 + f) * 256 + k;
    Wht[o] = hi; Wlt[o] = lo;
}

// ---------------------------------------------------------------------------
// MFMA GEMM (bf16x3 split) + fused attn projections + bf16 output.
// Block: 64 rows x 64 cols (one head), 4 waves as 2x2 of 32x32 tiles, K=32.
// Proj: per-row dot(acc, a_vec) reduced via shfl-16 (lanes l&15 = cols),
// cross-wave combine via atomicAdd into zeroed as_/at_ (fp32-accurate).
// ---------------------------------------------------------------------------
__global__ __launch_bounds__(256) void gemm_mfma_k(
    const u16* __restrict__ Xh, const u16* __restrict__ Xl,
    const u16* __restrict__ Wht, const u16* __restrict__ Wlt,  // pre-offset per layer
    const float* __restrict__ a_src, const float* __restrict__ a_trg,
    u16* __restrict__ HPB, float* __restrict__ as_, float* __restrict__ at_,
    int n)
{
    const int row0 = blockIdx.x * 64;
    const int h    = blockIdx.y;
    const int t = threadIdx.x;
    const int l = t & 63;
    const int wc = (t >> 6) & 1;
    const int wr = (t >> 7) & 1;

    __shared__ u16 Ah[64 * 40], Al[64 * 40], Bh[64 * 40], Bl[64 * 40];

    const int sr = t >> 2, sp = t & 3;
    const int arow = (row0 + sr < n) ? (row0 + sr) : (n - 1);
    const u16* gAh = Xh + (size_t)arow * 256 + sp * 8;
    const u16* gAl = Xl + (size_t)arow * 256 + sp * 8;
    const u16* gBh = Wht + (size_t)(h * 64 + sr) * 256 + sp * 8;
    const u16* gBl = Wlt + (size_t)(h * 64 + sr) * 256 + sp * 8;
    const int ldst = sr * 40 + sp * 8;

    const int ra0 = (wr * 32 + (l & 15)) * 40 + (l >> 4) * 8;
    const int ca0 = (wc * 32 + (l & 15)) * 40 + (l >> 4) * 8;

    f32x4 acc00 = {0.f, 0.f, 0.f, 0.f}, acc01 = acc00, acc10 = acc00, acc11 = acc00;

    for (int k0 = 0; k0 < 256; k0 += 32) {
        __syncthreads();
        *(u16x8*)&Ah[ldst] = *(const u16x8*)(gAh + k0);
        *(u16x8*)&Al[ldst] = *(const u16x8*)(gAl + k0);
        *(u16x8*)&Bh[ldst] = *(const u16x8*)(gBh + k0);
        *(u16x8*)&Bl[ldst] = *(const u16x8*)(gBl + k0);
        __syncthreads();

        s16x8 a0h = *(const s16x8*)&Ah[ra0];
        s16x8 a1h = *(const s16x8*)&Ah[ra0 + 640];
        s16x8 a0l = *(const s16x8*)&Al[ra0];
        s16x8 a1l = *(const s16x8*)&Al[ra0 + 640];
        s16x8 b0h = *(const s16x8*)&Bh[ca0];
        s16x8 b1h = *(const s16x8*)&Bh[ca0 + 640];
        s16x8 b0l = *(const s16x8*)&Bl[ca0];
        s16x8 b1l = *(const s16x8*)&Bl[ca0 + 640];

        acc00 = __builtin_amdgcn_mfma_f32_16x16x32_bf16(a0h, b0h, acc00, 0, 0, 0);
        acc01 = __builtin_amdgcn_mfma_f32_16x16x32_bf16(a0h, b1h, acc01, 0, 0, 0);
        acc10 = __builtin_amdgcn_mfma_f32_16x16x32_bf16(a1h, b0h, acc10, 0, 0, 0);
        acc11 = __builtin_amdgcn_mfma_f32_16x16x32_bf16(a1h, b1h, acc11, 0, 0, 0);
        acc00 = __builtin_amdgcn_mfma_f32_16x16x32_bf16(a0h, b0l, acc00, 0, 0, 0);
        acc01 = __builtin_amdgcn_mfma_f32_16x16x32_bf16(a0h, b1l, acc01, 0, 0, 0);
        acc10 = __builtin_amdgcn_mfma_f32_16x16x32_bf16(a1h, b0l, acc10, 0, 0, 0);
        acc11 = __builtin_amdgcn_mfma_f32_16x16x32_bf16(a1h, b1l, acc11, 0, 0, 0);
        acc00 = __builtin_amdgcn_mfma_f32_16x16x32_bf16(a0l, b0h, acc00, 0, 0, 0);
        acc01 = __builtin_amdgcn_mfma_f32_16x16x32_bf16(a0l, b1h, acc01, 0, 0, 0);
        acc10 = __builtin_amdgcn_mfma_f32_16x16x32_bf16(a1l, b0h, acc10, 0, 0, 0);
        acc11 = __builtin_amdgcn_mfma_f32_16x16x32_bf16(a1l, b1h, acc11, 0, 0, 0);
    }

    // epilogue: C/D col = l&15 (+16 for second frag), row = (l>>4)*4 + r
    const int cl = wc * 32 + (l & 15);        // col within head
    const int rb = row0 + wr * 32 + ((l >> 4) << 2);
    const float pa0 = a_src[h * 64 + cl], pa1 = a_src[h * 64 + cl + 16];
    const float pb0 = a_trg[h * 64 + cl], pb1 = a_trg[h * 64 + cl + 16];

    #pragma unroll
    for (int r = 0; r < 4; ++r) {
        int g0 = rb + r, g1 = rb + 16 + r;
        float s0 = acc00[r] * pa0 + acc01[r] * pa1;
        float t0 = acc00[r] * pb0 + acc01[r] * pb1;
        float s1 = acc10[r] * pa0 + acc11[r] * pa1;
        float t1 = acc10[r] * pb0 + acc11[r] * pb1;
        #pragma unroll
        for (int off = 8; off; off >>= 1) {
            s0 += __shfl_xor(s0, off, 16); t0 += __shfl_xor(t0, off, 16);
            s1 += __shfl_xor(s1, off, 16); t1 += __shfl_xor(t1, off, 16);
        }
        if (g0 < n) {
            HPB[(size_t)g0 * 256 + h * 64 + cl]      = f2bf(acc00[r]);
            HPB[(size_t)g0 * 256 + h * 64 + cl + 16] = f2bf(acc01[r]);
            if ((l & 15) == 0) {
                atomicAdd(&as_[g0 * 4 + h], s0);
                atomicAdd(&at_[g0 * 4 + h], t0);
            }
        }
        if (g1 < n) {
            HPB[(size_t)g1 * 256 + h * 64 + cl]      = f2bf(acc10[r]);
            HPB[(size_t)g1 * 256 + h * 64 + cl + 16] = f2bf(acc11[r]);
            if ((l & 15) == 0) {
                atomicAdd(&as_[g1 * 4 + h], s1);
                atomicAdd(&at_[g1 * 4 + h], t1);
            }
        }
    }
}

// ---------------------------------------------------------------------------
// CSR build, both sides in merged dispatches
// ---------------------------------------------------------------------------
__global__ void hist2_k(const int* __restrict__ tu, const int* __restrict__ tt,
                        int* __restrict__ counts, int* __restrict__ ranks,
                        int E, int N)
{
    int e = blockIdx.x * blockDim.x + threadIdx.x;
    if (e < E)          ranks[e] = atomicAdd(&counts[tu[e]], 1);
    else if (e < 2 * E) ranks[e] = atomicAdd(&counts[N + tt[e - E]], 1);
}

__global__ __launch_bounds__(1024) void scan2_k(const int* __restrict__ counts_all,
                                                int* __restrict__ starts_all, int n)
{
    const int T = 1024;
    const int* counts = counts_all + blockIdx.x * n;
    int* starts = starts_all + blockIdx.x * (n + 1);
    int t = threadIdx.x;
    int chunk = (n + T - 1) / T;
    int beg = t * chunk;
    int end = min(beg + chunk, n);
    int sum = 0;
    for (int i = beg; i < end; ++i) sum += counts[i];
    __shared__ int lds[T];
    lds[t] = sum;
    __syncthreads();
    for (int off = 1; off < T; off <<= 1) {
        int v = (t >= off) ? lds[t - off] : 0;
        __syncthreads();
        lds[t] += v;
        __syncthreads();
    }
    int run = lds[t] - sum;
    for (int i = beg; i < end; ++i) { starts[i] = run; run += counts[i]; }
    if (t == T - 1) starts[n] = lds[T - 1];
}

__global__ void scatter2_k(const int* __restrict__ su, const int* __restrict__ st,
                           const int* __restrict__ tu, const int* __restrict__ tt,
                           const int* __restrict__ starts_all,
                           const int* __restrict__ ranks, int* __restrict__ srcs,
                           int E, int N)
{
    int e = blockIdx.x * blockDim.x + threadIdx.x;
    if (e < E) {
        srcs[starts_all[tu[e]] + ranks[e]] = su[e];
    } else if (e < 2 * E) {
        int ee = e - E;
        const int* st1 = starts_all + (N + 1);
        srcs[E + st1[tt[ee]] + ranks[e]] = st[ee];
    }
}

// ---------------------------------------------------------------------------
// Aggregation: one WAVE per node, bf16 gather (512B rows), 4-edge unroll.
// lane l: cols 4l..4l+3 (head h=l>>4).
// LAYER 0: elu + bf16 hi/lo split -> oh/ol (feeds next GEMM directly).
// LAYER 1: head-mean -> of[n][64] fp32.
// ---------------------------------------------------------------------------
template<int LAYER>
__global__ __launch_bounds__(256) void aggregate_k(
    const u16* __restrict__ HPB, const float* __restrict__ as_,
    const float* __restrict__ at_, const int* __restrict__ starts,
    const int* __restrict__ srcs,
    u16* __restrict__ oh, u16* __restrict__ ol, float* __restrict__ of, int n)
{
    const int w = threadIdx.x >> 6;
    const int l = threadIdx.x & 63;
    const int v = blockIdx.x * 4 + w;
    if (v >= n) return;
    const int h = l >> 4;
    const int s0 = starts[v], s1 = starts[v + 1];
    const float atv = at_[v * 4 + h];
    const size_t lo4 = (size_t)l * 4;

    float4 ac0 = make_float4(0.f, 0.f, 0.f, 0.f), ac1 = ac0, ac2 = ac0, ac3 = ac0;
    float dn0 = 0.f, dn1 = 0.f, dn2 = 0.f, dn3 = 0.f;

    for (int base = s0; base < s1; base += 64) {
        int m = min(64, s1 - base);
        int s_l = (base + l < s1) ? srcs[base + l] : 0;
        int i = 0;
        for (; i + 3 < m; i += 4) {
            int sa = __shfl(s_l, i, 64);
            int sb = __shfl(s_l, i + 1, 64);
            int sc = __shfl(s_l, i + 2, 64);
            int sd = __shfl(s_l, i + 3, 64);
            u16x4 va = *(const u16x4*)(HPB + (size_t)sa * 256 + lo4);
            u16x4 vb = *(const u16x4*)(HPB + (size_t)sb * 256 + lo4);
            u16x4 vc = *(const u16x4*)(HPB + (size_t)sc * 256 + lo4);
            u16x4 vd = *(const u16x4*)(HPB + (size_t)sd * 256 + lo4);
            float ea = as_[sa * 4 + h] + atv;
            float eb = as_[sb * 4 + h] + atv;
            float ec = as_[sc * 4 + h] + atv;
            float ed = as_[sd * 4 + h] + atv;
            ea = (ea > 0.f) ? ea : NEG_SLOPE * ea;
            eb = (eb > 0.f) ? eb : NEG_SLOPE * eb;
            ec = (ec > 0.f) ? ec : NEG_SLOPE * ec;
            ed = (ed > 0.f) ? ed : NEG_SLOPE * ed;
            float pA = expf(ea), pB = expf(eb), pC = expf(ec), pD = expf(ed);
            dn0 += pA; dn1 += pB; dn2 += pC; dn3 += pD;
            ac0.x += pA * bf2f(va[0]); ac0.y += pA * bf2f(va[1]);
            ac0.z += pA * bf2f(va[2]); ac0.w += pA * bf2f(va[3]);
            ac1.x += pB * bf2f(vb[0]); ac1.y += pB * bf2f(vb[1]);
            ac1.z += pB * bf2f(vb[2]); ac1.w += pB * bf2f(vb[3]);
            ac2.x += pC * bf2f(vc[0]); ac2.y += pC * bf2f(vc[1]);
            ac2.z += pC * bf2f(vc[2]); ac2.w += pC * bf2f(vc[3]);
            ac3.x += pD * bf2f(vd[0]); ac3.y += pD * bf2f(vd[1]);
            ac3.z += pD * bf2f(vd[2]); ac3.w += pD * bf2f(vd[3]);
        }
        for (; i < m; ++i) {
            int sa = __shfl(s_l, i, 64);
            u16x4 va = *(const u16x4*)(HPB + (size_t)sa * 256 + lo4);
            float ea = as_[sa * 4 + h] + atv;
            ea = (ea > 0.f) ? ea : NEG_SLOPE * ea;
            float pA = expf(ea);
            dn0 += pA;
            ac0.x += pA * bf2f(va[0]); ac0.y += pA * bf2f(va[1]);
            ac0.z += pA * bf2f(va[2]); ac0.w += pA * bf2f(va[3]);
        }
    }

    float4 acc = make_float4(ac0.x + ac1.x + ac2.x + ac3.x,
                             ac0.y + ac1.y + ac2.y + ac3.y,
                             ac0.z + ac1.z + ac2.z + ac3.z,
                             ac0.w + ac1.w + ac2.w + ac3.w);
    float r = 1.f / (dn0 + dn1 + dn2 + dn3 + 1e-16f);
    acc.x *= r; acc.y *= r; acc.z *= r; acc.w *= r;

    if (LAYER == 0) {
        float f[4] = { acc.x, acc.y, acc.z, acc.w };
        u16x4 hi, lo;
        #pragma unroll
        for (int c = 0; c < 4; ++c) {
            float e = (f[c] > 0.f) ? f[c] : expm1f(f[c]);
            u16 hh = f2bf(e);
            hi[c] = hh;
            lo[c] = f2bf(e - bf2f(hh));
        }
        *(u16x4*)(oh + (size_t)v * 256 + lo4) = hi;
        *(u16x4*)(ol + (size_t)v * 256 + lo4) = lo;
    } else {
        acc.x += __shfl_xor(acc.x, 16, 64); acc.y += __shfl_xor(acc.y, 16, 64);
        acc.z += __shfl_xor(acc.z, 16, 64); acc.w += __shfl_xor(acc.w, 16, 64);
        acc.x += __shfl_xor(acc.x, 32, 64); acc.y += __shfl_xor(acc.y, 32, 64);
        acc.z += __shfl_xor(acc.z, 32, 64); acc.w += __shfl_xor(acc.w, 32, 64);
        if (l < 16) {
            acc.x *= 0.25f; acc.y *= 0.25f; acc.z *= 0.25f; acc.w *= 0.25f;
            *(float4*)(of + (size_t)v * 64 + l * 4) = acc;
        }
    }
}

// ---------------------------------------------------------------------------
// final: logits = [out_u | out_t] @ fc_w + fc_b ; log_softmax over 16
// ---------------------------------------------------------------------------
__global__ __launch_bounds__(256) void final_k(
    const float* __restrict__ out_u, const float* __restrict__ out_t,
    const float* __restrict__ fcw, const float* __restrict__ fcb,
    float* __restrict__ out, int nret)
{
    int gid = blockIdx.x * blockDim.x + threadIdx.x;
    int nn = gid >> 4;
    int j  = gid & 15;
    if (nn >= nret) return;
    const float* ru = out_u + (size_t)nn * 64;
    const float* rt = out_t + (size_t)nn * 64;
    float acc = fcb[j];
    #pragma unroll 8
    for (int k = 0; k < 64; ++k) acc += ru[k] * fcw[k * 16 + j];
    #pragma unroll 8
    for (int k = 0; k < 64; ++k) acc += rt[k] * fcw[(64 + k) * 16 + j];

    float m = acc;
    for (int off = 8; off; off >>= 1) m = fmaxf(m, __shfl_xor(m, off, 16));
    float ex = expf(acc - m);
    float s = ex;
    for (int off = 8; off; off >>= 1) s += __shfl_xor(s, off, 16);
    out[(size_t)nn * 16 + j] = acc - m - logf(s);
}

// ---------------------------------------------------------------------------
extern "C" void kernel_launch(void* const* d_in, const int* in_sizes, int n_in,
                              void* d_out, int out_size, void* d_ws, size_t ws_size,
                              hipStream_t stream)
{
    const int N = in_sizes[0] / 256;     // 20000
    const int E = in_sizes[2];           // 320000
    const int NRET = out_size / 16;      // 20000

    const float* emb[2]  = { (const float*)d_in[0], (const float*)d_in[1] };
    const int*   srcI[2] = { (const int*)d_in[2], (const int*)d_in[4] };
    const int*   trgI[2] = { (const int*)d_in[3], (const int*)d_in[5] };
    const float* fcw = (const float*)d_in[18];
    const float* fcb = (const float*)d_in[19];

    // workspace carve (all region sizes multiples of 16B)
    char* p = (char*)d_ws;
    u16* hpb = (u16*)p;   p += (size_t)N * 256 * 2;
    u16* xh  = (u16*)p;   p += (size_t)N * 256 * 2;
    u16* xl  = (u16*)p;   p += (size_t)N * 256 * 2;
    u16* wht = (u16*)p;   p += (size_t)4 * 65536 * 2;
    u16* wlt = (u16*)p;   p += (size_t)4 * 65536 * 2;
    float* asat = (float*)p; p += (size_t)N * 32 * 4;   // 4 (as,at) pairs
    float* out_s[2];
    out_s[0] = (float*)p; p += (size_t)N * 64 * 4;
    out_s[1] = (float*)p; p += (size_t)N * 64 * 4;
    int* starts2 = (int*)p; p += (size_t)2 * (N + 1) * 4;
    int* counts2 = (int*)p; p += (size_t)2 * N * 4;
    int* ranks2  = (int*)p; p += (size_t)2 * E * 4;
    int* srcs2   = (int*)p; p += (size_t)2 * E * 4;

    const int E2B = (2 * E + 255) / 256;
    const dim3 gemm_grid((N + 63) / 64, 4);
    const int split_blocks = (N * 64 + 255) / 256;
    const int agg_grid = (N + 3) / 4;

    // zero all atomic accumulators + histogram counters once
    hipMemsetAsync(asat, 0, (size_t)N * 32 * 4, stream);
    hipMemsetAsync(counts2, 0, (size_t)2 * N * 4, stream);

    // CSR for both sides
    hist2_k<<<E2B, 256, 0, stream>>>(trgI[0], trgI[1], counts2, ranks2, E, N);
    scan2_k<<<2, 1024, 0, stream>>>(counts2, starts2, N);
    scatter2_k<<<E2B, 256, 0, stream>>>(srcI[0], srcI[1], trgI[0], trgI[1],
                                        starts2, ranks2, srcs2, E, N);

    // all 4 weight splits
    wsplit4_k<<<1024, 256, 0, stream>>>(
        (const float*)d_in[6], (const float*)d_in[9],
        (const float*)d_in[12], (const float*)d_in[15], wht, wlt);

    for (int side = 0; side < 2; ++side) {
        const int* starts = starts2 + side * (N + 1);
        const int* srcs   = srcs2 + side * E;

        splitx_k<<<split_blocks, 256, 0, stream>>>(emb[side], xh, xl, N * 64);

        for (int layer = 0; layer < 2; ++layer) {
            const int which = side * 2 + layer;
            const float* asl = (const float*)d_in[6 + side * 6 + layer * 3 + 1];
            const float* atl = (const float*)d_in[6 + side * 6 + layer * 3 + 2];
            float* as_ = asat + (size_t)which * N * 8;
            float* at_ = as_ + (size_t)N * 4;

            gemm_mfma_k<<<gemm_grid, 256, 0, stream>>>(
                xh, xl, wht + (size_t)which * 65536, wlt + (size_t)which * 65536,
                asl, atl, hpb, as_, at_, N);

            if (layer == 0)
                aggregate_k<0><<<agg_grid, 256, 0, stream>>>(
                    hpb, as_, at_, starts, srcs, xh, xl, nullptr, N);
            else
                aggregate_k<1><<<agg_grid, 256, 0, stream>>>(
                    hpb, as_, at_, starts, srcs, nullptr, nullptr, out_s[side], N);
        }
    }

    final_k<<<(NRET * 16 + 255) / 256, 256, 0, stream>>>(out_s[0], out_s[1], fcw, fcb,
                                                         (float*)d_out, NRET);
}

// Round 8
// 384.414 us; speedup vs baseline: 2.9818x; 1.1787x over previous
//
#include <hip/hip_runtime.h>
#include <hip/hip_bf16.h>

#define NEG_SLOPE 0.2f

typedef unsigned short u16;
typedef u16 u16x8 __attribute__((ext_vector_type(8)));
typedef u16 u16x4 __attribute__((ext_vector_type(4)));
typedef short s16x8 __attribute__((ext_vector_type(8)));
typedef float f32x4 __attribute__((ext_vector_type(4)));

__device__ __forceinline__ u16 f2bf(float x) {
    unsigned u = __float_as_uint(x);
    return (u16)((u + 0x7fffu + ((u >> 16) & 1u)) >> 16);
}
__device__ __forceinline__ float bf2f(u16 h) {
    return __uint_as_float(((unsigned)h) << 16);
}

// ---------------------------------------------------------------------------
// split fp32 -> bf16 hi + lo(residual), both sides in one dispatch (grid.y)
// ---------------------------------------------------------------------------
__global__ __launch_bounds__(256) void splitx_k(
    const float* __restrict__ x0, const float* __restrict__ x1,
    u16* __restrict__ Xh, u16* __restrict__ Xl, int per_side4)
{
    int i = blockIdx.x * 256 + threadIdx.x;
    if (i >= per_side4) return;
    int side = blockIdx.y;
    const float* X = side ? x1 : x0;
    size_t o = (size_t)side * per_side4 * 4 + (size_t)i * 4;
    float4 v = *(const float4*)(X + (size_t)i * 4);
    float f[4] = { v.x, v.y, v.z, v.w };
    u16x4 hi, lo;
    #pragma unroll
    for (int j = 0; j < 4; ++j) {
        u16 h = f2bf(f[j]);
        hi[j] = h;
        lo[j] = f2bf(f[j] - bf2f(h));
    }
    *(u16x4*)(Xh + o) = hi;
    *(u16x4*)(Xl + o) = lo;
}

// ---------------------------------------------------------------------------
// all 4 weight tensors: W[h][k][f] -> Wct[which][col=h*64+f][k] hi/lo
// which = side*2+layer: {u0,u1,t0,t1}
// ---------------------------------------------------------------------------
__global__ __launch_bounds__(256) void wsplit4_k(
    const float* __restrict__ w0, const float* __restrict__ w1,
    const float* __restrict__ w2, const float* __restrict__ w3,
    u16* __restrict__ Wht, u16* __restrict__ Wlt)
{
    int tid = blockIdx.x * 256 + threadIdx.x;     // 0..262143
    int which = tid >> 16;
    int idx = tid & 65535;
    const float* W = (which == 0) ? w0 : (which == 1) ? w1 : (which == 2) ? w2 : w3;
    int f = idx & 63, k = (idx >> 6) & 255, h = idx >> 14;
    float x = W[idx];
    u16 hi = f2bf(x);
    u16 lo = f2bf(x - bf2f(hi));
    int o = (which << 16) + (h * 64 + f) * 256 + k;
    Wht[o] = hi; Wlt[o] = lo;
}

// ---------------------------------------------------------------------------
// MFMA GEMM v5 (bf16x3): block = 64 rows x 256 cols (ALL heads), wave = head.
// Both sides in one dispatch (blockIdx.y). K-step 32, LDS stride 40 u16.
// Per wave: 4 row-frags x 4 col-frags x 3 products = 48 MFMA / k-step.
// Fused attn projections: shfl-16 reduce, plain store (unique writer).
// ---------------------------------------------------------------------------
__global__ __launch_bounds__(256) void gemm_mfma_k(
    const u16* __restrict__ xh_all, const u16* __restrict__ xl_all,  // [2][n*256]
    const u16* __restrict__ Wht, const u16* __restrict__ Wlt,        // [4][65536]
    const float* __restrict__ au_s, const float* __restrict__ au_t,  // side u a_src/a_trg
    const float* __restrict__ at_s, const float* __restrict__ at_t,  // side t a_src/a_trg
    u16* __restrict__ hpb_all,                                       // [2][n*256]
    float* __restrict__ asat,                                        // [4][n*8]
    int layer, int n)
{
    const int side = blockIdx.y;
    const int row0 = blockIdx.x * 64;
    const int t = threadIdx.x;
    const int l = t & 63;
    const int h = t >> 6;                 // wave = head
    const int which = side * 2 + layer;

    const u16* Xh = xh_all + (size_t)side * n * 256;
    const u16* Xl = xl_all + (size_t)side * n * 256;
    const u16* Wh = Wht + ((size_t)which << 16);
    const u16* Wl = Wlt + ((size_t)which << 16);
    const float* a_src = (side ? at_s : au_s) + h * 64;
    const float* a_trg = (side ? at_t : au_t) + h * 64;
    u16* HPB = hpb_all + (size_t)side * n * 256;
    float* as_ = asat + (size_t)which * n * 8;
    float* at_ = as_ + (size_t)n * 4;

    __shared__ u16 Ah[64 * 40], Al[64 * 40], Bh[256 * 40], Bl[256 * 40];

    // A staging: thread t -> row sr=t>>2, k-chunk sp=t&3 (one u16x8 per array)
    const int sr = t >> 2, sp = t & 3;
    const int arow = (row0 + sr < n) ? (row0 + sr) : (n - 1);
    const u16* gAh = Xh + (size_t)arow * 256 + sp * 8;
    const u16* gAl = Xl + (size_t)arow * 256 + sp * 8;
    const int lda = sr * 40 + sp * 8;

    // frag addresses
    const int fb = l & 15;                // col/row within frag
    const int kg = l >> 4;                // k-group
    int ra[4], cb[4];
    #pragma unroll
    for (int r = 0; r < 4; ++r) ra[r] = (r * 16 + fb) * 40 + kg * 8;
    #pragma unroll
    for (int c = 0; c < 4; ++c) cb[c] = (h * 64 + c * 16 + fb) * 40 + kg * 8;

    f32x4 acc[4][4];
    #pragma unroll
    for (int r = 0; r < 4; ++r)
        #pragma unroll
        for (int c = 0; c < 4; ++c) acc[r][c] = f32x4{0.f, 0.f, 0.f, 0.f};

    for (int k0 = 0; k0 < 256; k0 += 32) {
        __syncthreads();
        *(u16x8*)&Ah[lda] = *(const u16x8*)(gAh + k0);
        *(u16x8*)&Al[lda] = *(const u16x8*)(gAl + k0);
        #pragma unroll
        for (int i = 0; i < 4; ++i) {
            int j = t + i * 256;              // 0..1023
            int col = j >> 2, cp = j & 3;
            int ofs = col * 40 + cp * 8;
            *(u16x8*)&Bh[ofs] = *(const u16x8*)(Wh + (size_t)col * 256 + k0 + cp * 8);
            *(u16x8*)&Bl[ofs] = *(const u16x8*)(Wl + (size_t)col * 256 + k0 + cp * 8);
        }
        __syncthreads();

        s16x8 bh[4], bl[4];
        #pragma unroll
        for (int c = 0; c < 4; ++c) {
            bh[c] = *(const s16x8*)&Bh[cb[c]];
            bl[c] = *(const s16x8*)&Bl[cb[c]];
        }
        #pragma unroll
        for (int r = 0; r < 4; ++r) {
            s16x8 ah = *(const s16x8*)&Ah[ra[r]];
            s16x8 al = *(const s16x8*)&Al[ra[r]];
            #pragma unroll
            for (int c = 0; c < 4; ++c) {
                acc[r][c] = __builtin_amdgcn_mfma_f32_16x16x32_bf16(ah, bh[c], acc[r][c], 0, 0, 0);
                acc[r][c] = __builtin_amdgcn_mfma_f32_16x16x32_bf16(ah, bl[c], acc[r][c], 0, 0, 0);
                acc[r][c] = __builtin_amdgcn_mfma_f32_16x16x32_bf16(al, bh[c], acc[r][c], 0, 0, 0);
            }
        }
    }

    // epilogue: row = row0 + r*16 + kg*4 + q ; col-in-head = c*16 + fb
    float pav[4], pbv[4];
    #pragma unroll
    for (int c = 0; c < 4; ++c) { pav[c] = a_src[c * 16 + fb]; pbv[c] = a_trg[c * 16 + fb]; }

    #pragma unroll
    for (int r = 0; r < 4; ++r) {
        #pragma unroll
        for (int q = 0; q < 4; ++q) {
            int grow = row0 + r * 16 + kg * 4 + q;
            float s = 0.f, u = 0.f;
            if (grow < n) {
                u16* hrow = HPB + (size_t)grow * 256 + h * 64 + fb;
                #pragma unroll
                for (int c = 0; c < 4; ++c) {
                    float v = acc[r][c][q];
                    s += v * pav[c];
                    u += v * pbv[c];
                    hrow[c * 16] = f2bf(v);
                }
            }
            #pragma unroll
            for (int off = 8; off; off >>= 1) {
                s += __shfl_xor(s, off, 16);
                u += __shfl_xor(u, off, 16);
            }
            if (grow < n && fb == 0) {
                as_[grow * 4 + h] = s;
                at_[grow * 4 + h] = u;
            }
        }
    }
}

// ---------------------------------------------------------------------------
// CSR build, both sides merged
// ---------------------------------------------------------------------------
__global__ void hist2_k(const int* __restrict__ tu, const int* __restrict__ tt,
                        int* __restrict__ counts, int* __restrict__ ranks,
                        int E, int N)
{
    int e = blockIdx.x * blockDim.x + threadIdx.x;
    if (e < E)          ranks[e] = atomicAdd(&counts[tu[e]], 1);
    else if (e < 2 * E) ranks[e] = atomicAdd(&counts[N + tt[e - E]], 1);
}

__global__ __launch_bounds__(1024) void scan2_k(const int* __restrict__ counts_all,
                                                int* __restrict__ starts_all, int n)
{
    const int T = 1024;
    const int* counts = counts_all + blockIdx.x * n;
    int* starts = starts_all + blockIdx.x * (n + 1);
    int t = threadIdx.x;
    int chunk = (n + T - 1) / T;
    int beg = t * chunk;
    int end = min(beg + chunk, n);
    int sum = 0;
    for (int i = beg; i < end; ++i) sum += counts[i];
    __shared__ int lds[T];
    lds[t] = sum;
    __syncthreads();
    for (int off = 1; off < T; off <<= 1) {
        int v = (t >= off) ? lds[t - off] : 0;
        __syncthreads();
        lds[t] += v;
        __syncthreads();
    }
    int run = lds[t] - sum;
    for (int i = beg; i < end; ++i) { starts[i] = run; run += counts[i]; }
    if (t == T - 1) starts[n] = lds[T - 1];
}

__global__ void scatter2_k(const int* __restrict__ su, const int* __restrict__ st,
                           const int* __restrict__ tu, const int* __restrict__ tt,
                           const int* __restrict__ starts_all,
                           const int* __restrict__ ranks, int* __restrict__ srcs,
                           int E, int N)
{
    int e = blockIdx.x * blockDim.x + threadIdx.x;
    if (e < E) {
        srcs[starts_all[tu[e]] + ranks[e]] = su[e];
    } else if (e < 2 * E) {
        int ee = e - E;
        const int* st1 = starts_all + (N + 1);
        srcs[E + st1[tt[ee]] + ranks[e]] = st[ee];
    }
}

// ---------------------------------------------------------------------------
// Aggregation: one WAVE per node, both sides (blockIdx.y), bf16 gather,
// 4-edge unroll. LAYER 0: elu+split -> xh/xl. LAYER 1: head-mean -> of.
// ---------------------------------------------------------------------------
template<int LAYER>
__global__ __launch_bounds__(256) void aggregate_k(
    const u16* __restrict__ hpb_all, const float* __restrict__ asat,
    const int* __restrict__ starts2, const int* __restrict__ srcs2,
    u16* __restrict__ oh_all, u16* __restrict__ ol_all,
    float* __restrict__ of_all, int n, int E)
{
    const int side = blockIdx.y;
    const int w = threadIdx.x >> 6;
    const int l = threadIdx.x & 63;
    const int v = blockIdx.x * 4 + w;
    if (v >= n) return;
    const int h = l >> 4;
    const int which = side * 2 + LAYER;

    const u16* HPB = hpb_all + (size_t)side * n * 256;
    const float* as_ = asat + (size_t)which * n * 8;
    const float* at_ = as_ + (size_t)n * 4;
    const int* starts = starts2 + side * (n + 1);
    const int* srcs = srcs2 + (size_t)side * E;

    const int s0 = starts[v], s1 = starts[v + 1];
    const float atv = at_[v * 4 + h];
    const size_t lo4 = (size_t)l * 4;

    float4 ac0 = make_float4(0.f, 0.f, 0.f, 0.f), ac1 = ac0, ac2 = ac0, ac3 = ac0;
    float dn0 = 0.f, dn1 = 0.f, dn2 = 0.f, dn3 = 0.f;

    for (int base = s0; base < s1; base += 64) {
        int m = min(64, s1 - base);
        int s_l = (base + l < s1) ? srcs[base + l] : 0;
        int i = 0;
        for (; i + 3 < m; i += 4) {
            int sa = __shfl(s_l, i, 64);
            int sb = __shfl(s_l, i + 1, 64);
            int sc = __shfl(s_l, i + 2, 64);
            int sd = __shfl(s_l, i + 3, 64);
            u16x4 va = *(const u16x4*)(HPB + (size_t)sa * 256 + lo4);
            u16x4 vb = *(const u16x4*)(HPB + (size_t)sb * 256 + lo4);
            u16x4 vc = *(const u16x4*)(HPB + (size_t)sc * 256 + lo4);
            u16x4 vd = *(const u16x4*)(HPB + (size_t)sd * 256 + lo4);
            float ea = as_[sa * 4 + h] + atv;
            float eb = as_[sb * 4 + h] + atv;
            float ec = as_[sc * 4 + h] + atv;
            float ed = as_[sd * 4 + h] + atv;
            ea = (ea > 0.f) ? ea : NEG_SLOPE * ea;
            eb = (eb > 0.f) ? eb : NEG_SLOPE * eb;
            ec = (ec > 0.f) ? ec : NEG_SLOPE * ec;
            ed = (ed > 0.f) ? ed : NEG_SLOPE * ed;
            float pA = expf(ea), pB = expf(eb), pC = expf(ec), pD = expf(ed);
            dn0 += pA; dn1 += pB; dn2 += pC; dn3 += pD;
            ac0.x += pA * bf2f(va[0]); ac0.y += pA * bf2f(va[1]);
            ac0.z += pA * bf2f(va[2]); ac0.w += pA * bf2f(va[3]);
            ac1.x += pB * bf2f(vb[0]); ac1.y += pB * bf2f(vb[1]);
            ac1.z += pB * bf2f(vb[2]); ac1.w += pB * bf2f(vb[3]);
            ac2.x += pC * bf2f(vc[0]); ac2.y += pC * bf2f(vc[1]);
            ac2.z += pC * bf2f(vc[2]); ac2.w += pC * bf2f(vc[3]);
            ac3.x += pD * bf2f(vd[0]); ac3.y += pD * bf2f(vd[1]);
            ac3.z += pD * bf2f(vd[2]); ac3.w += pD * bf2f(vd[3]);
        }
        for (; i < m; ++i) {
            int sa = __shfl(s_l, i, 64);
            u16x4 va = *(const u16x4*)(HPB + (size_t)sa * 256 + lo4);
            float ea = as_[sa * 4 + h] + atv;
            ea = (ea > 0.f) ? ea : NEG_SLOPE * ea;
            float pA = expf(ea);
            dn0 += pA;
            ac0.x += pA * bf2f(va[0]); ac0.y += pA * bf2f(va[1]);
            ac0.z += pA * bf2f(va[2]); ac0.w += pA * bf2f(va[3]);
        }
    }

    float4 acc = make_float4(ac0.x + ac1.x + ac2.x + ac3.x,
                             ac0.y + ac1.y + ac2.y + ac3.y,
                             ac0.z + ac1.z + ac2.z + ac3.z,
                             ac0.w + ac1.w + ac2.w + ac3.w);
    float r = 1.f / (dn0 + dn1 + dn2 + dn3 + 1e-16f);
    acc.x *= r; acc.y *= r; acc.z *= r; acc.w *= r;

    if (LAYER == 0) {
        u16* oh = oh_all + (size_t)side * n * 256;
        u16* ol = ol_all + (size_t)side * n * 256;
        float f[4] = { acc.x, acc.y, acc.z, acc.w };
        u16x4 hi, lo;
        #pragma unroll
        for (int c = 0; c < 4; ++c) {
            float e = (f[c] > 0.f) ? f[c] : expm1f(f[c]);
            u16 hh = f2bf(e);
            hi[c] = hh;
            lo[c] = f2bf(e - bf2f(hh));
        }
        *(u16x4*)(oh + (size_t)v * 256 + lo4) = hi;
        *(u16x4*)(ol + (size_t)v * 256 + lo4) = lo;
    } else {
        float* of = of_all + (size_t)side * n * 64;
        acc.x += __shfl_xor(acc.x, 16, 64); acc.y += __shfl_xor(acc.y, 16, 64);
        acc.z += __shfl_xor(acc.z, 16, 64); acc.w += __shfl_xor(acc.w, 16, 64);
        acc.x += __shfl_xor(acc.x, 32, 64); acc.y += __shfl_xor(acc.y, 32, 64);
        acc.z += __shfl_xor(acc.z, 32, 64); acc.w += __shfl_xor(acc.w, 32, 64);
        if (l < 16) {
            acc.x *= 0.25f; acc.y *= 0.25f; acc.z *= 0.25f; acc.w *= 0.25f;
            *(float4*)(of + (size_t)v * 64 + l * 4) = acc;
        }
    }
}

// ---------------------------------------------------------------------------
// final: logits = [out_u | out_t] @ fc_w + fc_b ; log_softmax over 16
// ---------------------------------------------------------------------------
__global__ __launch_bounds__(256) void final_k(
    const float* __restrict__ out_u, const float* __restrict__ out_t,
    const float* __restrict__ fcw, const float* __restrict__ fcb,
    float* __restrict__ out, int nret)
{
    int gid = blockIdx.x * blockDim.x + threadIdx.x;
    int nn = gid >> 4;
    int j  = gid & 15;
    if (nn >= nret) return;
    const float* ru = out_u + (size_t)nn * 64;
    const float* rt = out_t + (size_t)nn * 64;
    float acc = fcb[j];
    #pragma unroll 8
    for (int k = 0; k < 64; ++k) acc += ru[k] * fcw[k * 16 + j];
    #pragma unroll 8
    for (int k = 0; k < 64; ++k) acc += rt[k] * fcw[(64 + k) * 16 + j];

    float m = acc;
    for (int off = 8; off; off >>= 1) m = fmaxf(m, __shfl_xor(m, off, 16));
    float ex = expf(acc - m);
    float s = ex;
    for (int off = 8; off; off >>= 1) s += __shfl_xor(s, off, 16);
    out[(size_t)nn * 16 + j] = acc - m - logf(s);
}

// ---------------------------------------------------------------------------
extern "C" void kernel_launch(void* const* d_in, const int* in_sizes, int n_in,
                              void* d_out, int out_size, void* d_ws, size_t ws_size,
                              hipStream_t stream)
{
    const int N = in_sizes[0] / 256;     // 20000
    const int E = in_sizes[2];           // 320000
    const int NRET = out_size / 16;      // 20000

    const float* emb[2]  = { (const float*)d_in[0], (const float*)d_in[1] };
    const int*   srcI[2] = { (const int*)d_in[2], (const int*)d_in[4] };
    const int*   trgI[2] = { (const int*)d_in[3], (const int*)d_in[5] };
    const float* fcw = (const float*)d_in[18];
    const float* fcb = (const float*)d_in[19];

    // workspace carve (ws ~268MB; usage ~85MB)
    char* p = (char*)d_ws;
    u16* hpb  = (u16*)p;    p += (size_t)2 * N * 256 * 2;
    u16* xh   = (u16*)p;    p += (size_t)2 * N * 256 * 2;
    u16* xl   = (u16*)p;    p += (size_t)2 * N * 256 * 2;
    u16* wht  = (u16*)p;    p += (size_t)4 * 65536 * 2;
    u16* wlt  = (u16*)p;    p += (size_t)4 * 65536 * 2;
    float* asat = (float*)p; p += (size_t)4 * N * 8 * 4;
    float* outs = (float*)p; p += (size_t)2 * N * 64 * 4;
    int* starts2 = (int*)p; p += (size_t)2 * (N + 1) * 4;
    int* counts2 = (int*)p; p += (size_t)2 * N * 4;
    int* ranks2  = (int*)p; p += (size_t)2 * E * 4;
    int* srcs2   = (int*)p; p += (size_t)2 * E * 4;

    const int E2B = (2 * E + 255) / 256;
    const dim3 gemm_grid((N + 63) / 64, 2);
    const dim3 split_grid((N * 64 + 255) / 256, 2);
    const dim3 agg_grid((N + 3) / 4, 2);

    hipMemsetAsync(counts2, 0, (size_t)2 * N * 4, stream);

    // CSR for both sides
    hist2_k<<<E2B, 256, 0, stream>>>(trgI[0], trgI[1], counts2, ranks2, E, N);
    scan2_k<<<2, 1024, 0, stream>>>(counts2, starts2, N);
    scatter2_k<<<E2B, 256, 0, stream>>>(srcI[0], srcI[1], trgI[0], trgI[1],
                                        starts2, ranks2, srcs2, E, N);

    // all 4 weight splits (u0,u1,t0,t1)
    wsplit4_k<<<1024, 256, 0, stream>>>(
        (const float*)d_in[6], (const float*)d_in[9],
        (const float*)d_in[12], (const float*)d_in[15], wht, wlt);

    // both embeddings -> bf16 hi/lo
    splitx_k<<<split_grid, 256, 0, stream>>>(emb[0], emb[1], xh, xl, N * 64);

    for (int layer = 0; layer < 2; ++layer) {
        const float* au_s = (const float*)d_in[6 + 0 * 6 + layer * 3 + 1];
        const float* au_t = (const float*)d_in[6 + 0 * 6 + layer * 3 + 2];
        const float* at_s = (const float*)d_in[6 + 1 * 6 + layer * 3 + 1];
        const float* at_t = (const float*)d_in[6 + 1 * 6 + layer * 3 + 2];

        gemm_mfma_k<<<gemm_grid, 256, 0, stream>>>(
            xh, xl, wht, wlt, au_s, au_t, at_s, at_t, hpb, asat, layer, N);

        if (layer == 0)
            aggregate_k<0><<<agg_grid, 256, 0, stream>>>(
                hpb, asat, starts2, srcs2, xh, xl, nullptr, N, E);
        else
            aggregate_k<1><<<agg_grid, 256, 0, stream>>>(
                hpb, asat, starts2, srcs2, nullptr, nullptr, outs, N, E);
    }

    final_k<<<(NRET * 16 + 255) / 256, 256, 0, stream>>>(
        outs, outs + (size_t)N * 64, fcw, fcb, (float*)d_out, NRET);
}